// Round 9
// baseline (3631.739 us; speedup 1.0000x reference)
//
#include <hip/hip_runtime.h>
#include <hip/hip_bf16.h>

#define TSTEPS 512
#define BATCH  64
#define DIM    512
#define NWG    8

using short8 = __attribute__((ext_vector_type(8))) short;
using f32x4  = __attribute__((ext_vector_type(4))) float;

__device__ __forceinline__ unsigned short f2bf(float f) {
    unsigned u = __builtin_bit_cast(unsigned, f);
    unsigned r = (u + 0x7FFFu + ((u >> 16) & 1u)) >> 16;   // RNE
    return (unsigned short)r;
}

// ---------- fp32 [a][b] -> bf16 [b][a]  (for xh and o) ----------
__global__ void conv_T(const float* __restrict__ src, unsigned short* __restrict__ dst) {
    __shared__ float tile[32][33];
    const int bx = blockIdx.x * 32, by = blockIdx.y * 32;
    const int tx = threadIdx.x & 31, ty = threadIdx.x >> 5;
#pragma unroll
    for (int k = 0; k < 32; k += 8)
        tile[ty + k][tx] = src[(size_t)(by + ty + k) * DIM + bx + tx];
    __syncthreads();
#pragma unroll
    for (int k = 0; k < 32; k += 8)
        dst[(size_t)(bx + ty + k) * DIM + by + tx] = f2bf(tile[tx][ty + k]);
}

// ---------- XW = x @ xh + hb (bf16 MFMA) -> d_out, layout [t][wv][kg][col] float4(r) ----------
__global__ __launch_bounds__(256) void gemm_xwm(
    const float* __restrict__ X,            // [32768][512] fp32
    const unsigned short* __restrict__ Bt,  // xhT bf16 [col][k]
    const float* __restrict__ bias, float* __restrict__ Out)
{
    __shared__ unsigned short As[128 * 40];
    __shared__ unsigned short Bs[128 * 40];
    const int tid = threadIdx.x;
    const int m0 = blockIdx.x * 128, n0 = blockIdx.y * 128;
    const int lane = tid & 63, wv = tid >> 6;
    const int ln15 = lane & 15, kg = lane >> 4;
    const int wr = (wv >> 1) * 64, wc = (wv & 1) * 64;

    f32x4 acc[4][4];
#pragma unroll
    for (int m = 0; m < 4; ++m)
#pragma unroll
        for (int n = 0; n < 4; ++n) acc[m][n] = f32x4{0.f, 0.f, 0.f, 0.f};

    const int arow = tid >> 1, ahalf = tid & 1;      // 2 threads/row, 16 elements each
    for (int k0 = 0; k0 < DIM; k0 += 32) {
        const float4* ga = reinterpret_cast<const float4*>(
            X + (size_t)(m0 + arow) * DIM + k0 + ahalf * 16);
        float4 a0 = ga[0], a1 = ga[1], a2 = ga[2], a3 = ga[3];
        const ulonglong2* gb = reinterpret_cast<const ulonglong2*>(
            Bt + (size_t)(n0 + arow) * DIM + k0 + ahalf * 16);
        ulonglong2 bv0 = gb[0], bv1 = gb[1];
        __syncthreads();
        {
            unsigned long long p[4];
            const float4 av[4] = {a0, a1, a2, a3};
#pragma unroll
            for (int q = 0; q < 4; ++q)
                p[q] = (unsigned long long)f2bf(av[q].x)
                     | ((unsigned long long)f2bf(av[q].y) << 16)
                     | ((unsigned long long)f2bf(av[q].z) << 32)
                     | ((unsigned long long)f2bf(av[q].w) << 48);
            unsigned long long* s = reinterpret_cast<unsigned long long*>(&As[arow * 40 + ahalf * 16]);
            s[0] = p[0]; s[1] = p[1]; s[2] = p[2]; s[3] = p[3];
            *reinterpret_cast<ulonglong2*>(&Bs[arow * 40 + ahalf * 16]) = bv0;
            *reinterpret_cast<ulonglong2*>(&Bs[arow * 40 + ahalf * 16 + 8]) = bv1;
        }
        __syncthreads();
        short8 af[4], bf[4];
#pragma unroll
        for (int m = 0; m < 4; ++m)
            af[m] = *reinterpret_cast<const short8*>(&As[(wr + m * 16 + ln15) * 40 + kg * 8]);
#pragma unroll
        for (int n = 0; n < 4; ++n)
            bf[n] = *reinterpret_cast<const short8*>(&Bs[(wc + n * 16 + ln15) * 40 + kg * 8]);
#pragma unroll
        for (int m = 0; m < 4; ++m)
#pragma unroll
            for (int n = 0; n < 4; ++n)
                acc[m][n] = __builtin_amdgcn_mfma_f32_16x16x32_bf16(af[m], bf[n], acc[m][n], 0, 0, 0);
    }
    // epilogue: row = m0+wr + m*16 + kg*4 + r  ->  t = row>>6, wv_out = m
    float4* Out4 = reinterpret_cast<float4*>(Out);
#pragma unroll
    for (int n = 0; n < 4; ++n) {
        int col = n0 + wc + n * 16 + ln15;
        float bb = bias[col];
#pragma unroll
        for (int m = 0; m < 4; ++m) {
            int t = (m0 + wr) >> 6;
            float4 v;
            v.x = acc[m][n][0] + bb; v.y = acc[m][n][1] + bb;
            v.z = acc[m][n][2] + bb; v.w = acc[m][n][3] + bb;
            Out4[(((size_t)t * 4 + m) * 4 + kg) * DIM + col] = v;
        }
    }
}

// ---------- persistent scan: arrival-driven K-chunks, wave-autonomous ----------
// Wave (wg,wv): owns output rows [16wv,+16) x cols [64wg,+64). Holds hh[:, its 64 cols]
// as 64 B-fragments (256 VGPR). Per step: sweep 8 chunk-flags (one lane-indexed atomic
// load + ballot); for each ready chunk j load 4 u64 of H rows (agent atomics, register-
// direct) and run its 8 MFMA. Store H_{t+1} (paired u32 agent atomics) into hist[t+1],
// drain, bump own flag. hist slices never reused -> no overwrite race, hang-free.
__global__ __launch_bounds__(256, 1) void rnn_scan(
    const float* __restrict__ hh, const float* __restrict__ xwb,
    const float* __restrict__ h0, unsigned short* hist,
    unsigned int* flags)
{
    const int tid  = threadIdx.x;
    const int wg   = blockIdx.x;
    const int lane = tid & 63;
    const int wv   = __builtin_amdgcn_readfirstlane(tid >> 6);
    const int ln15 = lane & 15, kg = lane >> 4;
    const bool even = (ln15 & 1) == 0;

    // B-fragments: Bhh[n][kk], col = 64wg + n*16 + ln15, k = kk*32 + kg*8 + j
    short8 Bhh[4][16];
#pragma unroll
    for (int n = 0; n < 4; ++n) {
        const int col = wg * 64 + n * 16 + ln15;
#pragma unroll
        for (int kk = 0; kk < 16; ++kk) {
            short8 b;
#pragma unroll
            for (int j = 0; j < 8; ++j)
                b[j] = (short)f2bf(hh[(size_t)(kk * 32 + kg * 8 + j) * DIM + col]);
            Bhh[n][kk] = b;
        }
    }

    // ---- prefill hist[0]: rows [16wv,+16) x cols [64wg,+64) from h0 (broadcast) ----
    {
        unsigned* hd32 = reinterpret_cast<unsigned*>(hist);   // slice 0
#pragma unroll
        for (int n = 0; n < 4; ++n) {
            int col = wg * 64 + n * 16 + ln15;
            unsigned self = f2bf(h0[col]);
            unsigned partner = (unsigned)__shfl_xor((int)self, 1);
            unsigned pair = even ? (self | (partner << 16)) : (partner | (self << 16));
            if (even == (n < 2)) {
                int colp = col >> 1;
#pragma unroll
                for (int r = 0; r < 4; ++r) {
                    int row = 16 * wv + kg * 4 + r;
                    __hip_atomic_store(&hd32[row * 256 + colp], pair,
                                       __ATOMIC_RELAXED, __HIP_MEMORY_SCOPE_AGENT);
                }
            }
        }
    }
    asm volatile("s_waitcnt vmcnt(0)" ::: "memory");
    if (lane == 0)
        __hip_atomic_store(&flags[wg * 4 + wv], 1u, __ATOMIC_RELAXED, __HIP_MEMORY_SCOPE_AGENT);

    const float4* xw4 = reinterpret_cast<const float4*>(xwb);
    typedef union { unsigned long long u[2]; short8 s; } cvt8;

    for (int t = 0; t < TSTEPS; ++t) {
        // XW for this step (plain loads; consumed after chunk loop -> latency hidden)
        f32x4 xw_[4];
#pragma unroll
        for (int n = 0; n < 4; ++n) {
            float4 v = xw4[(((size_t)t * 4 + wv) * 4 + kg) * DIM + wg * 64 + n * 16 + ln15];
            xw_[n] = f32x4{v.x, v.y, v.z, v.w};
        }

        f32x4 acc[4];
#pragma unroll
        for (int n = 0; n < 4; ++n) acc[n] = f32x4{0.f, 0.f, 0.f, 0.f};

        const unsigned long long* hrow = reinterpret_cast<const unsigned long long*>(
            hist + (size_t)t * (BATCH * DIM) + (size_t)(16 * wv + ln15) * DIM);
        const unsigned expect = (unsigned)(t + 1);

        unsigned done = 0;
        while (done != 0xffu) {
            unsigned fl = __hip_atomic_load(&flags[(lane & 7) * 4 + wv],
                                            __ATOMIC_RELAXED, __HIP_MEMORY_SCOPE_AGENT);
            unsigned long long bal = __ballot(fl >= expect);
            unsigned ready = ((unsigned)bal & 0xffu) & ~done;
            if (ready == 0) { __builtin_amdgcn_s_sleep(1); continue; }
#pragma unroll
            for (int j = 0; j < 8; ++j) {
                if (ready & (1u << j)) {
                    cvt8 a0, a1;   // kk = 2j, 2j+1 : u64 index kk*8 + kg*2 (+1)
                    a0.u[0] = __hip_atomic_load(hrow + (2 * j) * 8 + kg * 2,
                                                __ATOMIC_RELAXED, __HIP_MEMORY_SCOPE_AGENT);
                    a0.u[1] = __hip_atomic_load(hrow + (2 * j) * 8 + kg * 2 + 1,
                                                __ATOMIC_RELAXED, __HIP_MEMORY_SCOPE_AGENT);
                    a1.u[0] = __hip_atomic_load(hrow + (2 * j + 1) * 8 + kg * 2,
                                                __ATOMIC_RELAXED, __HIP_MEMORY_SCOPE_AGENT);
                    a1.u[1] = __hip_atomic_load(hrow + (2 * j + 1) * 8 + kg * 2 + 1,
                                                __ATOMIC_RELAXED, __HIP_MEMORY_SCOPE_AGENT);
#pragma unroll
                    for (int n = 0; n < 4; ++n) {
                        acc[n] = __builtin_amdgcn_mfma_f32_16x16x32_bf16(a0.s, Bhh[n][2 * j],     acc[n], 0, 0, 0);
                        acc[n] = __builtin_amdgcn_mfma_f32_16x16x32_bf16(a1.s, Bhh[n][2 * j + 1], acc[n], 0, 0, 0);
                    }
                }
            }
            done |= ready;
        }

        // ---- H_{t+1} = relu(XW + acc) -> hist[t+1] (paired u32 agent atomics) ----
        unsigned* hd32 = reinterpret_cast<unsigned*>(hist + (size_t)(t + 1) * (BATCH * DIM));
#pragma unroll
        for (int n = 0; n < 4; ++n) {
            int col = wg * 64 + n * 16 + ln15;
            int colp = col >> 1;
#pragma unroll
            for (int r = 0; r < 4; ++r) {
                float hn = xw_[n][r] + acc[n][r];
                hn = hn > 0.f ? hn : 0.f;
                unsigned self = f2bf(hn);
                unsigned partner = (unsigned)__shfl_xor((int)self, 1);
                unsigned pair = even ? (self | (partner << 16)) : (partner | (self << 16));
                if (even == (n < 2)) {
                    int row = 16 * wv + kg * 4 + r;
                    __hip_atomic_store(&hd32[row * 256 + colp], pair,
                                       __ATOMIC_RELAXED, __HIP_MEMORY_SCOPE_AGENT);
                }
            }
        }
        asm volatile("s_waitcnt vmcnt(0)" ::: "memory");   // drain before flag bump
        if (lane == 0)
            __hip_atomic_store(&flags[wg * 4 + wv], (unsigned)(t + 2),
                               __ATOMIC_RELAXED, __HIP_MEMORY_SCOPE_AGENT);
    }
}

// ---------- Y = Hist(slices 1..512) @ o : MFMA GEMM, 128x128x32 tiles ----------
__global__ __launch_bounds__(256) void gemm_y(
    const unsigned short* __restrict__ A,   // hist + 32768: [32768][512] bf16
    const unsigned short* __restrict__ Bt,  // oT bf16 [col][k]
    float* __restrict__ Out)                // [32768][512] fp32
{
    __shared__ unsigned short As[128 * 40];
    __shared__ unsigned short Bs[128 * 40];
    const int tid = threadIdx.x;
    const int m0 = blockIdx.x * 128, n0 = blockIdx.y * 128;
    const int lane = tid & 63, wv = tid >> 6;
    const int ln15 = lane & 15, kg = lane >> 4;
    const int wr = (wv >> 1) * 64, wc = (wv & 1) * 64;

    f32x4 acc[4][4];
#pragma unroll
    for (int m = 0; m < 4; ++m)
#pragma unroll
        for (int n = 0; n < 4; ++n) acc[m][n] = f32x4{0.f, 0.f, 0.f, 0.f};

    const int sr = tid & 127;
    for (int k0 = 0; k0 < DIM; k0 += 32) {
        const unsigned short* g = (tid < 128)
            ? A  + (size_t)(m0 + sr) * DIM + k0
            : Bt + (size_t)(n0 + sr) * DIM + k0;
        unsigned short* s = (tid < 128) ? &As[sr * 40] : &Bs[sr * 40];
        ulonglong2 v0 = reinterpret_cast<const ulonglong2*>(g)[0];
        ulonglong2 v1 = reinterpret_cast<const ulonglong2*>(g)[1];
        ulonglong2 v2 = reinterpret_cast<const ulonglong2*>(g)[2];
        ulonglong2 v3 = reinterpret_cast<const ulonglong2*>(g)[3];
        __syncthreads();
        reinterpret_cast<ulonglong2*>(s)[0] = v0;
        reinterpret_cast<ulonglong2*>(s)[1] = v1;
        reinterpret_cast<ulonglong2*>(s)[2] = v2;
        reinterpret_cast<ulonglong2*>(s)[3] = v3;
        __syncthreads();
        short8 af[4], bf[4];
#pragma unroll
        for (int m = 0; m < 4; ++m)
            af[m] = *reinterpret_cast<const short8*>(&As[(wr + m * 16 + ln15) * 40 + kg * 8]);
#pragma unroll
        for (int n = 0; n < 4; ++n)
            bf[n] = *reinterpret_cast<const short8*>(&Bs[(wc + n * 16 + ln15) * 40 + kg * 8]);
#pragma unroll
        for (int m = 0; m < 4; ++m)
#pragma unroll
            for (int n = 0; n < 4; ++n)
                acc[m][n] = __builtin_amdgcn_mfma_f32_16x16x32_bf16(af[m], bf[n], acc[m][n], 0, 0, 0);
    }
#pragma unroll
    for (int m = 0; m < 4; ++m)
#pragma unroll
        for (int n = 0; n < 4; ++n)
#pragma unroll
            for (int r = 0; r < 4; ++r) {
                int row = m0 + wr + m * 16 + kg * 4 + r;
                int col = n0 + wc + n * 16 + ln15;
                Out[(size_t)row * DIM + col] = acc[m][n][r];
            }
}

extern "C" void kernel_launch(void* const* d_in, const int* in_sizes, int n_in,
                              void* d_out, int out_size, void* d_ws, size_t ws_size,
                              hipStream_t stream) {
    const float* x  = (const float*)d_in[0];
    const float* xh = (const float*)d_in[1];
    const float* hh = (const float*)d_in[2];
    const float* hb = (const float*)d_in[3];
    const float* o  = (const float*)d_in[4];
    const float* h0 = (const float*)d_in[5];
    float* out = (float*)d_out;

    unsigned int* flags = (unsigned int*)d_ws;                          // 32 x u32
    unsigned short* hist = (unsigned short*)((char*)d_ws + 4096);       // 513 * 64KB
    unsigned short* oT  = (unsigned short*)((char*)d_ws + 4096 + (size_t)513 * 65536);
    unsigned short* xhT = oT + (size_t)DIM * DIM;

    (void)hipMemsetAsync(d_ws, 0, 4096, stream);
    conv_T<<<dim3(16, 16), 256, 0, stream>>>(o, oT);
    conv_T<<<dim3(16, 16), 256, 0, stream>>>(xh, xhT);
    gemm_xwm<<<dim3(256, 4), 256, 0, stream>>>(x, xhT, hb, out);   // out <- XWB ([t][wv][kg][col] r-packed)
    rnn_scan<<<NWG, 256, 0, stream>>>(hh, out, h0, hist, flags);
    gemm_y<<<dim3(256, 4), 256, 0, stream>>>(hist + 32768, oT, out);  // out <- Y
}

// Round 10
// 3116.256 us; speedup vs baseline: 1.1654x; 1.1654x over previous
//
#include <hip/hip_runtime.h>
#include <hip/hip_bf16.h>

#define TSTEPS 512
#define BATCH  64
#define DIM    512
#define NWG    8
#define NWG_LAUNCH 128

using short8 = __attribute__((ext_vector_type(8))) short;
using f32x4  = __attribute__((ext_vector_type(4))) float;

__device__ __forceinline__ unsigned short f2bf(float f) {
    unsigned u = __builtin_bit_cast(unsigned, f);
    unsigned r = (u + 0x7FFFu + ((u >> 16) & 1u)) >> 16;   // RNE
    return (unsigned short)r;
}

// ---------- fp32 [a][b] -> bf16 [b][a]  (for xh and o) ----------
__global__ void conv_T(const float* __restrict__ src, unsigned short* __restrict__ dst) {
    __shared__ float tile[32][33];
    const int bx = blockIdx.x * 32, by = blockIdx.y * 32;
    const int tx = threadIdx.x & 31, ty = threadIdx.x >> 5;
#pragma unroll
    for (int k = 0; k < 32; k += 8)
        tile[ty + k][tx] = src[(size_t)(by + ty + k) * DIM + bx + tx];
    __syncthreads();
#pragma unroll
    for (int k = 0; k < 32; k += 8)
        dst[(size_t)(bx + ty + k) * DIM + by + tx] = f2bf(tile[tx][ty + k]);
}

// ---------- XW = x @ xh + hb (bf16 MFMA) -> d_out, layout [t][wv][kg][col] float4(r) ----------
__global__ __launch_bounds__(256) void gemm_xwm(
    const float* __restrict__ X,            // [32768][512] fp32
    const unsigned short* __restrict__ Bt,  // xhT bf16 [col][k]
    const float* __restrict__ bias, float* __restrict__ Out)
{
    __shared__ unsigned short As[128 * 40];
    __shared__ unsigned short Bs[128 * 40];
    const int tid = threadIdx.x;
    const int m0 = blockIdx.x * 128, n0 = blockIdx.y * 128;
    const int lane = tid & 63, wv = tid >> 6;
    const int ln15 = lane & 15, kg = lane >> 4;
    const int wr = (wv >> 1) * 64, wc = (wv & 1) * 64;

    f32x4 acc[4][4];
#pragma unroll
    for (int m = 0; m < 4; ++m)
#pragma unroll
        for (int n = 0; n < 4; ++n) acc[m][n] = f32x4{0.f, 0.f, 0.f, 0.f};

    const int arow = tid >> 1, ahalf = tid & 1;
    for (int k0 = 0; k0 < DIM; k0 += 32) {
        const float4* ga = reinterpret_cast<const float4*>(
            X + (size_t)(m0 + arow) * DIM + k0 + ahalf * 16);
        float4 a0 = ga[0], a1 = ga[1], a2 = ga[2], a3 = ga[3];
        const ulonglong2* gb = reinterpret_cast<const ulonglong2*>(
            Bt + (size_t)(n0 + arow) * DIM + k0 + ahalf * 16);
        ulonglong2 bv0 = gb[0], bv1 = gb[1];
        __syncthreads();
        {
            unsigned long long p[4];
            const float4 av[4] = {a0, a1, a2, a3};
#pragma unroll
            for (int q = 0; q < 4; ++q)
                p[q] = (unsigned long long)f2bf(av[q].x)
                     | ((unsigned long long)f2bf(av[q].y) << 16)
                     | ((unsigned long long)f2bf(av[q].z) << 32)
                     | ((unsigned long long)f2bf(av[q].w) << 48);
            unsigned long long* s = reinterpret_cast<unsigned long long*>(&As[arow * 40 + ahalf * 16]);
            s[0] = p[0]; s[1] = p[1]; s[2] = p[2]; s[3] = p[3];
            *reinterpret_cast<ulonglong2*>(&Bs[arow * 40 + ahalf * 16]) = bv0;
            *reinterpret_cast<ulonglong2*>(&Bs[arow * 40 + ahalf * 16 + 8]) = bv1;
        }
        __syncthreads();
        short8 af[4], bf[4];
#pragma unroll
        for (int m = 0; m < 4; ++m)
            af[m] = *reinterpret_cast<const short8*>(&As[(wr + m * 16 + ln15) * 40 + kg * 8]);
#pragma unroll
        for (int n = 0; n < 4; ++n)
            bf[n] = *reinterpret_cast<const short8*>(&Bs[(wc + n * 16 + ln15) * 40 + kg * 8]);
#pragma unroll
        for (int m = 0; m < 4; ++m)
#pragma unroll
            for (int n = 0; n < 4; ++n)
                acc[m][n] = __builtin_amdgcn_mfma_f32_16x16x32_bf16(af[m], bf[n], acc[m][n], 0, 0, 0);
    }
    float4* Out4 = reinterpret_cast<float4*>(Out);
#pragma unroll
    for (int n = 0; n < 4; ++n) {
        int col = n0 + wc + n * 16 + ln15;
        float bb = bias[col];
#pragma unroll
        for (int m = 0; m < 4; ++m) {
            int t = (m0 + wr) >> 6;
            float4 v;
            v.x = acc[m][n][0] + bb; v.y = acc[m][n][1] + bb;
            v.z = acc[m][n][2] + bb; v.w = acc[m][n][3] + bb;
            Out4[(((size_t)t * 4 + m) * 4 + kg) * DIM + col] = v;
        }
    }
}

// ---------- persistent scan: 8 WGs elected onto ONE XCD; data via shared L2 ----------
// Election: leaderless, deadlock-free (agent RMWs only). Data: plain stores/loads
// (write-through L1 -> shared L2; hist addresses never re-read so L1 can't be stale).
// Flags: agent-scope RMW poll (coherence point, never L1-cached). If the same-XCD
// assumption breaks, result is wrong (caught by harness), not a hang.
__global__ __launch_bounds__(256, 1) void rnn_scan(
    const float* __restrict__ hh, const float* __restrict__ xwb,
    const float* __restrict__ h0, unsigned short* hist,
    unsigned int* flags, unsigned int* ectrl)
{
    __shared__ int s_rank;
    const int tid = threadIdx.x;

    if (tid == 0) {
        unsigned xcd;
        asm volatile("s_getreg_b32 %0, hwreg(HW_REG_XCC_ID)" : "=s"(xcd));
        xcd &= 7u;
        unsigned myrank = __hip_atomic_fetch_add(&ectrl[xcd], 1u,
                              __ATOMIC_RELAXED, __HIP_MEMORY_SCOPE_AGENT);
        __hip_atomic_fetch_add(&ectrl[8], 1u, __ATOMIC_RELEASE, __HIP_MEMORY_SCOPE_AGENT);
        while (__hip_atomic_fetch_add(&ectrl[8], 0u,
                   __ATOMIC_ACQUIRE, __HIP_MEMORY_SCOPE_AGENT) < (unsigned)NWG_LAUNCH)
            __builtin_amdgcn_s_sleep(8);
        unsigned best = 0, bc = 0;
#pragma unroll
        for (int i = 0; i < 8; ++i) {
            unsigned c = __hip_atomic_fetch_add(&ectrl[i], 0u,
                             __ATOMIC_RELAXED, __HIP_MEMORY_SCOPE_AGENT);
            if (c > bc) { bc = c; best = (unsigned)i; }
        }
        s_rank = (xcd == best && myrank < (unsigned)NWG) ? (int)myrank : -1;
    }
    __syncthreads();
    const int wg = s_rank;
    if (wg < 0) return;

    const int lane = tid & 63;
    const int wv   = __builtin_amdgcn_readfirstlane(tid >> 6);
    const int ln15 = lane & 15, kg = lane >> 4;
    const bool even = (ln15 & 1) == 0;

    // hh columns -> B-fragments (col = 64wg + n*16 + ln15, k = kk*32 + kg*8 + j)
    short8 Bhh[4][16];
#pragma unroll
    for (int n = 0; n < 4; ++n) {
        const int col = wg * 64 + n * 16 + ln15;
#pragma unroll
        for (int kk = 0; kk < 16; ++kk) {
            short8 b;
#pragma unroll
            for (int j = 0; j < 8; ++j)
                b[j] = (short)f2bf(hh[(size_t)(kk * 32 + kg * 8 + j) * DIM + col]);
            Bhh[n][kk] = b;
        }
    }

    // prefill hist[0]: rows [16wv,+16) x cols [64wg,+64), h0 broadcast over batch
    {
        unsigned* hd32 = reinterpret_cast<unsigned*>(hist);
#pragma unroll
        for (int n = 0; n < 4; ++n) {
            int col = wg * 64 + n * 16 + ln15;
            unsigned self = f2bf(h0[col]);
            unsigned partner = (unsigned)__shfl_xor((int)self, 1);
            unsigned pair = even ? (self | (partner << 16)) : (partner | (self << 16));
            if (even == (n < 2)) {
                int colp = col >> 1;
#pragma unroll
                for (int r = 0; r < 4; ++r)
                    hd32[(16 * wv + kg * 4 + r) * 256 + colp] = pair;   // plain -> L2
            }
        }
    }
    asm volatile("s_waitcnt vmcnt(0)" ::: "memory");
    if (lane == 0)
        __hip_atomic_store(&flags[(wg * 4 + wv) * 16], 1u,
                           __ATOMIC_RELAXED, __HIP_MEMORY_SCOPE_AGENT);

    const float4* xw4 = reinterpret_cast<const float4*>(xwb);

    for (int t = 0; t < TSTEPS; ++t) {
        // XW plain loads (cold addresses), issued before the poll to hide latency
        f32x4 xw_[4];
#pragma unroll
        for (int n = 0; n < 4; ++n) {
            float4 v = xw4[(((size_t)t * 4 + wv) * 4 + kg) * DIM + wg * 64 + n * 16 + ln15];
            xw_[n] = f32x4{v.x, v.y, v.z, v.w};
        }
        asm volatile("" ::: "memory");   // keep XW loads above the poll

        // poll: all 8 producer flags (same wv) >= t+1, via agent RMW (never stale)
        {
            unsigned* fp = &flags[((lane & 7) * 4 + wv) * 16];
            for (;;) {
                unsigned fl = __hip_atomic_fetch_add(fp, 0u,
                                  __ATOMIC_RELAXED, __HIP_MEMORY_SCOPE_AGENT);
                if (!__any(fl < (unsigned)(t + 1))) break;
                __builtin_amdgcn_s_sleep(1);
            }
        }
        asm volatile("" ::: "memory");   // keep data loads below the poll

        // A-fragments straight from shared L2 (plain dwordx4 loads), fully unrolled MFMA
        const short8* hv = reinterpret_cast<const short8*>(
            hist + (size_t)t * (BATCH * DIM) + (size_t)(16 * wv + ln15) * DIM);
        f32x4 acc[4];
#pragma unroll
        for (int n = 0; n < 4; ++n) acc[n] = f32x4{0.f, 0.f, 0.f, 0.f};
#pragma unroll
        for (int kk = 0; kk < 16; ++kk) {
            short8 a = hv[kk * 4 + kg];
#pragma unroll
            for (int n = 0; n < 4; ++n)
                acc[n] = __builtin_amdgcn_mfma_f32_16x16x32_bf16(a, Bhh[n][kk], acc[n], 0, 0, 0);
        }

        // H_{t+1} = relu(XW + acc) -> hist[t+1] (plain paired-u32 stores -> shared L2)
        unsigned* hd32 = reinterpret_cast<unsigned*>(hist + (size_t)(t + 1) * (BATCH * DIM));
#pragma unroll
        for (int n = 0; n < 4; ++n) {
            int col = wg * 64 + n * 16 + ln15;
            int colp = col >> 1;
#pragma unroll
            for (int r = 0; r < 4; ++r) {
                float hn = xw_[n][r] + acc[n][r];
                hn = hn > 0.f ? hn : 0.f;
                unsigned self = f2bf(hn);
                unsigned partner = (unsigned)__shfl_xor((int)self, 1);
                unsigned pair = even ? (self | (partner << 16)) : (partner | (self << 16));
                if (even == (n < 2))
                    hd32[(16 * wv + kg * 4 + r) * 256 + colp] = pair;
            }
        }
        if (t < TSTEPS - 1) {
            asm volatile("s_waitcnt vmcnt(0)" ::: "memory");   // data in L2 before flag
            if (lane == 0)
                __hip_atomic_store(&flags[(wg * 4 + wv) * 16], (unsigned)(t + 2),
                                   __ATOMIC_RELAXED, __HIP_MEMORY_SCOPE_AGENT);
        }
        // t = TSTEPS-1: hist[512] visible to gemm_y via kernel-end release
    }
}

// ---------- Y = Hist(slices 1..512) @ o : MFMA GEMM, 128x128x32 tiles ----------
__global__ __launch_bounds__(256) void gemm_y(
    const unsigned short* __restrict__ A,   // hist + 32768: [32768][512] bf16
    const unsigned short* __restrict__ Bt,  // oT bf16 [col][k]
    float* __restrict__ Out)                // [32768][512] fp32
{
    __shared__ unsigned short As[128 * 40];
    __shared__ unsigned short Bs[128 * 40];
    const int tid = threadIdx.x;
    const int m0 = blockIdx.x * 128, n0 = blockIdx.y * 128;
    const int lane = tid & 63, wv = tid >> 6;
    const int ln15 = lane & 15, kg = lane >> 4;
    const int wr = (wv >> 1) * 64, wc = (wv & 1) * 64;

    f32x4 acc[4][4];
#pragma unroll
    for (int m = 0; m < 4; ++m)
#pragma unroll
        for (int n = 0; n < 4; ++n) acc[m][n] = f32x4{0.f, 0.f, 0.f, 0.f};

    const int sr = tid & 127;
    for (int k0 = 0; k0 < DIM; k0 += 32) {
        const unsigned short* g = (tid < 128)
            ? A  + (size_t)(m0 + sr) * DIM + k0
            : Bt + (size_t)(n0 + sr) * DIM + k0;
        unsigned short* s = (tid < 128) ? &As[sr * 40] : &Bs[sr * 40];
        ulonglong2 v0 = reinterpret_cast<const ulonglong2*>(g)[0];
        ulonglong2 v1 = reinterpret_cast<const ulonglong2*>(g)[1];
        ulonglong2 v2 = reinterpret_cast<const ulonglong2*>(g)[2];
        ulonglong2 v3 = reinterpret_cast<const ulonglong2*>(g)[3];
        __syncthreads();
        reinterpret_cast<ulonglong2*>(s)[0] = v0;
        reinterpret_cast<ulonglong2*>(s)[1] = v1;
        reinterpret_cast<ulonglong2*>(s)[2] = v2;
        reinterpret_cast<ulonglong2*>(s)[3] = v3;
        __syncthreads();
        short8 af[4], bf[4];
#pragma unroll
        for (int m = 0; m < 4; ++m)
            af[m] = *reinterpret_cast<const short8*>(&As[(wr + m * 16 + ln15) * 40 + kg * 8]);
#pragma unroll
        for (int n = 0; n < 4; ++n)
            bf[n] = *reinterpret_cast<const short8*>(&Bs[(wc + n * 16 + ln15) * 40 + kg * 8]);
#pragma unroll
        for (int m = 0; m < 4; ++m)
#pragma unroll
            for (int n = 0; n < 4; ++n)
                acc[m][n] = __builtin_amdgcn_mfma_f32_16x16x32_bf16(af[m], bf[n], acc[m][n], 0, 0, 0);
    }
#pragma unroll
    for (int m = 0; m < 4; ++m)
#pragma unroll
        for (int n = 0; n < 4; ++n)
#pragma unroll
            for (int r = 0; r < 4; ++r) {
                int row = m0 + wr + m * 16 + kg * 4 + r;
                int col = n0 + wc + n * 16 + ln15;
                Out[(size_t)row * DIM + col] = acc[m][n][r];
            }
}

extern "C" void kernel_launch(void* const* d_in, const int* in_sizes, int n_in,
                              void* d_out, int out_size, void* d_ws, size_t ws_size,
                              hipStream_t stream) {
    const float* x  = (const float*)d_in[0];
    const float* xh = (const float*)d_in[1];
    const float* hh = (const float*)d_in[2];
    const float* hb = (const float*)d_in[3];
    const float* o  = (const float*)d_in[4];
    const float* h0 = (const float*)d_in[5];
    float* out = (float*)d_out;

    unsigned int* flags = (unsigned int*)d_ws;                          // 32 x 64B slots
    unsigned int* ectrl = (unsigned int*)((char*)d_ws + 2048);          // xcnt[8] + total
    unsigned short* hist = (unsigned short*)((char*)d_ws + 4096);       // 513 * 64KB
    unsigned short* oT  = (unsigned short*)((char*)d_ws + 4096 + (size_t)513 * 65536);
    unsigned short* xhT = oT + (size_t)DIM * DIM;

    (void)hipMemsetAsync(d_ws, 0, 4096, stream);
    conv_T<<<dim3(16, 16), 256, 0, stream>>>(o, oT);
    conv_T<<<dim3(16, 16), 256, 0, stream>>>(xh, xhT);
    gemm_xwm<<<dim3(256, 4), 256, 0, stream>>>(x, xhT, hb, out);
    rnn_scan<<<NWG_LAUNCH, 256, 0, stream>>>(hh, out, h0, hist, flags, ectrl);
    gemm_y<<<dim3(256, 4), 256, 0, stream>>>(hist + 32768, oT, out);
}

// Round 11
// 2745.150 us; speedup vs baseline: 1.3230x; 1.1352x over previous
//
#include <hip/hip_runtime.h>
#include <hip/hip_bf16.h>

#define TSTEPS 512
#define BATCH  64
#define DIM    512
#define NWG    8
#define NWG_LAUNCH 128

using short8 = __attribute__((ext_vector_type(8))) short;
using f32x4  = __attribute__((ext_vector_type(4))) float;

__device__ __forceinline__ unsigned short f2bf(float f) {
    unsigned u = __builtin_bit_cast(unsigned, f);
    unsigned r = (u + 0x7FFFu + ((u >> 16) & 1u)) >> 16;   // RNE
    return (unsigned short)r;
}

// L2-point atomics (sc1=0 -> executed at the local XCD's L2, never stale, ~250cy).
// Correct here because ALL participants are elected onto one XCD.
__device__ __forceinline__ unsigned l2_fetch_add(unsigned* p, unsigned v) {
    unsigned old;
    asm volatile("global_atomic_add %0, %1, %2, off sc0\n\ts_waitcnt vmcnt(0)"
                 : "=v"(old) : "v"(p), "v"(v) : "memory");
    return old;
}
__device__ __forceinline__ void l2_add(unsigned* p, unsigned v) {
    asm volatile("global_atomic_add %0, %1, off" :: "v"(p), "v"(v) : "memory");
}

// ---------- fp32 [a][b] -> bf16 [b][a]  (for xh and o) ----------
__global__ void conv_T(const float* __restrict__ src, unsigned short* __restrict__ dst) {
    __shared__ float tile[32][33];
    const int bx = blockIdx.x * 32, by = blockIdx.y * 32;
    const int tx = threadIdx.x & 31, ty = threadIdx.x >> 5;
#pragma unroll
    for (int k = 0; k < 32; k += 8)
        tile[ty + k][tx] = src[(size_t)(by + ty + k) * DIM + bx + tx];
    __syncthreads();
#pragma unroll
    for (int k = 0; k < 32; k += 8)
        dst[(size_t)(bx + ty + k) * DIM + by + tx] = f2bf(tile[tx][ty + k]);
}

// ---------- XW = x @ xh + hb (bf16 MFMA) -> d_out, layout [t][wv][kg][col] float4(r) ----------
__global__ __launch_bounds__(256) void gemm_xwm(
    const float* __restrict__ X,            // [32768][512] fp32
    const unsigned short* __restrict__ Bt,  // xhT bf16 [col][k]
    const float* __restrict__ bias, float* __restrict__ Out)
{
    __shared__ unsigned short As[128 * 40];
    __shared__ unsigned short Bs[128 * 40];
    const int tid = threadIdx.x;
    const int m0 = blockIdx.x * 128, n0 = blockIdx.y * 128;
    const int lane = tid & 63, wv = tid >> 6;
    const int ln15 = lane & 15, kg = lane >> 4;
    const int wr = (wv >> 1) * 64, wc = (wv & 1) * 64;

    f32x4 acc[4][4];
#pragma unroll
    for (int m = 0; m < 4; ++m)
#pragma unroll
        for (int n = 0; n < 4; ++n) acc[m][n] = f32x4{0.f, 0.f, 0.f, 0.f};

    const int arow = tid >> 1, ahalf = tid & 1;
    for (int k0 = 0; k0 < DIM; k0 += 32) {
        const float4* ga = reinterpret_cast<const float4*>(
            X + (size_t)(m0 + arow) * DIM + k0 + ahalf * 16);
        float4 a0 = ga[0], a1 = ga[1], a2 = ga[2], a3 = ga[3];
        const ulonglong2* gb = reinterpret_cast<const ulonglong2*>(
            Bt + (size_t)(n0 + arow) * DIM + k0 + ahalf * 16);
        ulonglong2 bv0 = gb[0], bv1 = gb[1];
        __syncthreads();
        {
            unsigned long long p[4];
            const float4 av[4] = {a0, a1, a2, a3};
#pragma unroll
            for (int q = 0; q < 4; ++q)
                p[q] = (unsigned long long)f2bf(av[q].x)
                     | ((unsigned long long)f2bf(av[q].y) << 16)
                     | ((unsigned long long)f2bf(av[q].z) << 32)
                     | ((unsigned long long)f2bf(av[q].w) << 48);
            unsigned long long* s = reinterpret_cast<unsigned long long*>(&As[arow * 40 + ahalf * 16]);
            s[0] = p[0]; s[1] = p[1]; s[2] = p[2]; s[3] = p[3];
            *reinterpret_cast<ulonglong2*>(&Bs[arow * 40 + ahalf * 16]) = bv0;
            *reinterpret_cast<ulonglong2*>(&Bs[arow * 40 + ahalf * 16 + 8]) = bv1;
        }
        __syncthreads();
        short8 af[4], bf[4];
#pragma unroll
        for (int m = 0; m < 4; ++m)
            af[m] = *reinterpret_cast<const short8*>(&As[(wr + m * 16 + ln15) * 40 + kg * 8]);
#pragma unroll
        for (int n = 0; n < 4; ++n)
            bf[n] = *reinterpret_cast<const short8*>(&Bs[(wc + n * 16 + ln15) * 40 + kg * 8]);
#pragma unroll
        for (int m = 0; m < 4; ++m)
#pragma unroll
            for (int n = 0; n < 4; ++n)
                acc[m][n] = __builtin_amdgcn_mfma_f32_16x16x32_bf16(af[m], bf[n], acc[m][n], 0, 0, 0);
    }
    float4* Out4 = reinterpret_cast<float4*>(Out);
#pragma unroll
    for (int n = 0; n < 4; ++n) {
        int col = n0 + wc + n * 16 + ln15;
        float bb = bias[col];
#pragma unroll
        for (int m = 0; m < 4; ++m) {
            int t = (m0 + wr) >> 6;
            float4 v;
            v.x = acc[m][n][0] + bb; v.y = acc[m][n][1] + bb;
            v.z = acc[m][n][2] + bb; v.w = acc[m][n][3] + bb;
            Out4[(((size_t)t * 4 + m) * 4 + kg) * DIM + col] = v;
        }
    }
}

// ---------- persistent scan: 8 WGs on ONE XCD; data plain-L2, flags L2-point RMW ----------
__global__ __launch_bounds__(256, 1) void rnn_scan(
    const float* __restrict__ hh, const float* __restrict__ xwb,
    const float* __restrict__ h0, unsigned short* hist,
    unsigned int* flags, unsigned int* ectrl)
{
    __shared__ int s_rank;
    const int tid = threadIdx.x;

    if (tid == 0) {
        unsigned xcd;
        asm volatile("s_getreg_b32 %0, hwreg(HW_REG_XCC_ID)" : "=s"(xcd));
        xcd &= 7u;
        unsigned myrank = __hip_atomic_fetch_add(&ectrl[xcd], 1u,
                              __ATOMIC_RELAXED, __HIP_MEMORY_SCOPE_AGENT);
        __hip_atomic_fetch_add(&ectrl[8], 1u, __ATOMIC_RELEASE, __HIP_MEMORY_SCOPE_AGENT);
        while (__hip_atomic_fetch_add(&ectrl[8], 0u,
                   __ATOMIC_ACQUIRE, __HIP_MEMORY_SCOPE_AGENT) < (unsigned)NWG_LAUNCH)
            __builtin_amdgcn_s_sleep(8);
        unsigned best = 0, bc = 0;
#pragma unroll
        for (int i = 0; i < 8; ++i) {
            unsigned c = __hip_atomic_fetch_add(&ectrl[i], 0u,
                             __ATOMIC_RELAXED, __HIP_MEMORY_SCOPE_AGENT);
            if (c > bc) { bc = c; best = (unsigned)i; }
        }
        s_rank = (xcd == best && myrank < (unsigned)NWG) ? (int)myrank : -1;
    }
    __syncthreads();
    const int wg = s_rank;
    if (wg < 0) return;

    const int lane = tid & 63;
    const int wv   = __builtin_amdgcn_readfirstlane(tid >> 6);
    const int ln15 = lane & 15, kg = lane >> 4;
    const bool even = (ln15 & 1) == 0;

    // hh columns -> B-fragments (col = 64wg + n*16 + ln15, k = kk*32 + kg*8 + j)
    short8 Bhh[4][16];
#pragma unroll
    for (int n = 0; n < 4; ++n) {
        const int col = wg * 64 + n * 16 + ln15;
#pragma unroll
        for (int kk = 0; kk < 16; ++kk) {
            short8 b;
#pragma unroll
            for (int j = 0; j < 8; ++j)
                b[j] = (short)f2bf(hh[(size_t)(kk * 32 + kg * 8 + j) * DIM + col]);
            Bhh[n][kk] = b;
        }
    }

    // prefill hist[0]: rows [16wv,+16) x cols [64wg,+64), h0 broadcast over batch
    {
        unsigned* hd32 = reinterpret_cast<unsigned*>(hist);
#pragma unroll
        for (int n = 0; n < 4; ++n) {
            int col = wg * 64 + n * 16 + ln15;
            unsigned self = f2bf(h0[col]);
            unsigned partner = (unsigned)__shfl_xor((int)self, 1);
            unsigned pair = even ? (self | (partner << 16)) : (partner | (self << 16));
            if (even == (n < 2)) {
                int colp = col >> 1;
#pragma unroll
                for (int r = 0; r < 4; ++r)
                    hd32[(16 * wv + kg * 4 + r) * 256 + colp] = pair;   // plain -> L2
            }
        }
    }
    asm volatile("s_waitcnt vmcnt(0)" ::: "memory");
    if (lane == 0) l2_add(&flags[(wg * 4 + wv) * 16], 1u);   // flag value 1 = slice 0 ready

    const float4* xw4 = reinterpret_cast<const float4*>(xwb);

    for (int t = 0; t < TSTEPS; ++t) {
        // XW plain loads (HBM), issued before the poll to hide latency
        f32x4 xw_[4];
#pragma unroll
        for (int n = 0; n < 4; ++n) {
            float4 v = xw4[(((size_t)t * 4 + wv) * 4 + kg) * DIM + wg * 64 + n * 16 + ln15];
            xw_[n] = f32x4{v.x, v.y, v.z, v.w};
        }
        asm volatile("" ::: "memory");

        // poll: producer-wave flags (same wv) >= t+1; lanes 0-7 only, L2-point RMW
        {
            unsigned* fp = &flags[((lane & 7) * 4 + wv) * 16];
            const unsigned target = (unsigned)(t + 1);
            for (;;) {
                unsigned fl = target;
                if (lane < 8) fl = l2_fetch_add(fp, 0u);
                if (!__any(fl < target)) break;
                __builtin_amdgcn_s_sleep(1);
            }
        }
        asm volatile("" ::: "memory");

        // A-fragments straight from shared L2 (plain dwordx4 loads), fully unrolled MFMA
        const short8* hv = reinterpret_cast<const short8*>(
            hist + (size_t)t * (BATCH * DIM) + (size_t)(16 * wv + ln15) * DIM);
        f32x4 acc[4];
#pragma unroll
        for (int n = 0; n < 4; ++n) acc[n] = f32x4{0.f, 0.f, 0.f, 0.f};
#pragma unroll
        for (int kk = 0; kk < 16; ++kk) {
            short8 a = hv[kk * 4 + kg];
#pragma unroll
            for (int n = 0; n < 4; ++n)
                acc[n] = __builtin_amdgcn_mfma_f32_16x16x32_bf16(a, Bhh[n][kk], acc[n], 0, 0, 0);
        }

        // H_{t+1} = relu(XW + acc) -> hist[t+1] (plain paired-u32 stores -> shared L2)
        unsigned* hd32 = reinterpret_cast<unsigned*>(hist + (size_t)(t + 1) * (BATCH * DIM));
#pragma unroll
        for (int n = 0; n < 4; ++n) {
            int col = wg * 64 + n * 16 + ln15;
            int colp = col >> 1;
#pragma unroll
            for (int r = 0; r < 4; ++r) {
                float hn = xw_[n][r] + acc[n][r];
                hn = hn > 0.f ? hn : 0.f;
                unsigned self = f2bf(hn);
                unsigned partner = (unsigned)__shfl_xor((int)self, 1);
                unsigned pair = even ? (self | (partner << 16)) : (partner | (self << 16));
                if (even == (n < 2))
                    hd32[(16 * wv + kg * 4 + r) * 256 + colp] = pair;
            }
        }
        if (t < TSTEPS - 1) {
            asm volatile("s_waitcnt vmcnt(0)" ::: "memory");   // data in L2 before flag
            if (lane == 0) l2_add(&flags[(wg * 4 + wv) * 16], 1u);
        }
        // t = TSTEPS-1: hist[512] visible to gemm_y via kernel-end release
    }
}

// ---------- Y = Hist(slices 1..512) @ o : MFMA GEMM, 128x128x32 tiles ----------
__global__ __launch_bounds__(256) void gemm_y(
    const unsigned short* __restrict__ A,   // hist + 32768: [32768][512] bf16
    const unsigned short* __restrict__ Bt,  // oT bf16 [col][k]
    float* __restrict__ Out)                // [32768][512] fp32
{
    __shared__ unsigned short As[128 * 40];
    __shared__ unsigned short Bs[128 * 40];
    const int tid = threadIdx.x;
    const int m0 = blockIdx.x * 128, n0 = blockIdx.y * 128;
    const int lane = tid & 63, wv = tid >> 6;
    const int ln15 = lane & 15, kg = lane >> 4;
    const int wr = (wv >> 1) * 64, wc = (wv & 1) * 64;

    f32x4 acc[4][4];
#pragma unroll
    for (int m = 0; m < 4; ++m)
#pragma unroll
        for (int n = 0; n < 4; ++n) acc[m][n] = f32x4{0.f, 0.f, 0.f, 0.f};

    const int sr = tid & 127;
    for (int k0 = 0; k0 < DIM; k0 += 32) {
        const unsigned short* g = (tid < 128)
            ? A  + (size_t)(m0 + sr) * DIM + k0
            : Bt + (size_t)(n0 + sr) * DIM + k0;
        unsigned short* s = (tid < 128) ? &As[sr * 40] : &Bs[sr * 40];
        ulonglong2 v0 = reinterpret_cast<const ulonglong2*>(g)[0];
        ulonglong2 v1 = reinterpret_cast<const ulonglong2*>(g)[1];
        ulonglong2 v2 = reinterpret_cast<const ulonglong2*>(g)[2];
        ulonglong2 v3 = reinterpret_cast<const ulonglong2*>(g)[3];
        __syncthreads();
        reinterpret_cast<ulonglong2*>(s)[0] = v0;
        reinterpret_cast<ulonglong2*>(s)[1] = v1;
        reinterpret_cast<ulonglong2*>(s)[2] = v2;
        reinterpret_cast<ulonglong2*>(s)[3] = v3;
        __syncthreads();
        short8 af[4], bf[4];
#pragma unroll
        for (int m = 0; m < 4; ++m)
            af[m] = *reinterpret_cast<const short8*>(&As[(wr + m * 16 + ln15) * 40 + kg * 8]);
#pragma unroll
        for (int n = 0; n < 4; ++n)
            bf[n] = *reinterpret_cast<const short8*>(&Bs[(wc + n * 16 + ln15) * 40 + kg * 8]);
#pragma unroll
        for (int m = 0; m < 4; ++m)
#pragma unroll
            for (int n = 0; n < 4; ++n)
                acc[m][n] = __builtin_amdgcn_mfma_f32_16x16x32_bf16(af[m], bf[n], acc[m][n], 0, 0, 0);
    }
#pragma unroll
    for (int m = 0; m < 4; ++m)
#pragma unroll
        for (int n = 0; n < 4; ++n)
#pragma unroll
            for (int r = 0; r < 4; ++r) {
                int row = m0 + wr + m * 16 + kg * 4 + r;
                int col = n0 + wc + n * 16 + ln15;
                Out[(size_t)row * DIM + col] = acc[m][n][r];
            }
}

extern "C" void kernel_launch(void* const* d_in, const int* in_sizes, int n_in,
                              void* d_out, int out_size, void* d_ws, size_t ws_size,
                              hipStream_t stream) {
    const float* x  = (const float*)d_in[0];
    const float* xh = (const float*)d_in[1];
    const float* hh = (const float*)d_in[2];
    const float* hb = (const float*)d_in[3];
    const float* o  = (const float*)d_in[4];
    const float* h0 = (const float*)d_in[5];
    float* out = (float*)d_out;

    unsigned int* flags = (unsigned int*)d_ws;                          // 32 x 64B slots
    unsigned int* ectrl = (unsigned int*)((char*)d_ws + 2048);          // xcnt[8] + total
    unsigned short* hist = (unsigned short*)((char*)d_ws + 4096);       // 513 * 64KB
    unsigned short* oT  = (unsigned short*)((char*)d_ws + 4096 + (size_t)513 * 65536);
    unsigned short* xhT = oT + (size_t)DIM * DIM;

    (void)hipMemsetAsync(d_ws, 0, 4096, stream);
    conv_T<<<dim3(16, 16), 256, 0, stream>>>(o, oT);
    conv_T<<<dim3(16, 16), 256, 0, stream>>>(xh, xhT);
    gemm_xwm<<<dim3(256, 4), 256, 0, stream>>>(x, xhT, hb, out);
    rnn_scan<<<NWG_LAUNCH, 256, 0, stream>>>(hh, out, h0, hist, flags, ectrl);
    gemm_y<<<dim3(256, 4), 256, 0, stream>>>(hist + 32768, oT, out);
}